// Round 5
// baseline (83.299 us; speedup 1.0000x reference)
//
#include <hip/hip_runtime.h>
#include <stdint.h>

#define HV 384
#define WV 384
#define HF 96
#define WF 96
#define NC 128
#define NB 32
#define NSTORM 50
#define TFRAMES 12
#define MIN_INT 0.3f

// peak tile geometry
#define TW 64
#define TH 32
#define GX (WV / TW)          // 6
#define GY (HV / TH)          // 12
#define GT (GX * GY)          // 72 tiles per batch
#define LCAP 256              // >= max real peaks per tile (~60 observed)

// selection
#define SELCAP 4096
#define NLISTS 512
#define SSZ 8                 // keys per list
#define LSTR 9                // list stride (8 + pad)

__device__ __forceinline__ int reflect_idx(int g, int n) {
    if (g < 0) return -g - 1;
    if (g >= n) return 2 * n - 1 - g;
    return g;
}

// ---- slow scalar peak predicate, used only on the dead fallback path
__device__ __forceinline__ bool is_peak(const float* __restrict__ vb, int p) {
    int i = p / WV, j = p % WV;
    float v = vb[p];
    if (!(v > MIN_INT)) return false;
    for (int dr = -4; dr <= 3; ++dr) {
        const float* row = vb + reflect_idx(i + dr, HV) * WV;
        for (int dc = -4; dc <= 3; ++dc)
            if (row[reflect_idx(j + dc, WV)] > v) return false;
    }
    return true;
}

// ---- kernel 1: separable 8x8 max filter on LDS tiles; float4 staging;
// per-tile candidate slots (NO global atomics, NO memset needed — every
// tcnt slot is written every launch).
// key = (float_bits(v) << 32) | ~idx — strict total order -> deterministic
// selection regardless of intra-tile compaction order.
__global__ void peak_kernel(const float* __restrict__ vil,
                            uint64_t* __restrict__ cand,
                            int* __restrict__ tcnt) {
    __shared__ __align__(16) float A[TH + 7][TW + 8];  // tile + halo
    __shared__ float Bm[TH + 7][TW];                   // horizontal max
    __shared__ uint64_t lkeys[LCAP];
    __shared__ int lcnt;

    int b = blockIdx.z, bx = blockIdx.x;
    int tx0 = bx * TW, ty0 = blockIdx.y * TH;
    int tile = blockIdx.y * GX + bx;
    int tid = threadIdx.x;                 // 256 threads
    const float* vb = vil + ((size_t)b * TFRAMES + (TFRAMES - 1)) * (HV * WV);

    if (tid == 0) lcnt = 0;

    // float4 staging; row reflect is pointer-only, keeps 16B alignment.
    int c0   = (bx == 0) ? 0 : tx0 - 4;               // multiple of 4
    int nf4  = (bx == 0 || bx == GX - 1) ? 17 : 18;
    int aoff = c0 - (tx0 - 4);                        // 0 or 4
    for (int k = tid; k < (TH + 7) * nf4; k += 256) {
        int r = k / nf4, q = k - r * nf4;
        int gr = reflect_idx(ty0 + r - 4, HV);
        float4 vv = *(const float4*)(vb + (size_t)gr * WV + c0 + 4 * q);
        *(float4*)&A[r][aoff + 4 * q] = vv;
    }
    int nl = aoff;
    int rstart = aoff + 4 * nf4;
    int nr = 71 - rstart; if (nr < 0) nr = 0;
    int ns = nl + nr;
    if (ns) for (int k = tid; k < (TH + 7) * ns; k += 256) {
        int r = k / ns, s = k - r * ns;
        int c = (s < nl) ? s : rstart + (s - nl);
        int gr = reflect_idx(ty0 + r - 4, HV);
        int gc = reflect_idx(tx0 + c - 4, WV);
        A[r][c] = vb[(size_t)gr * WV + gc];
    }
    __syncthreads();

    // horizontal: Bm[r][c] = max(A[r][c..c+7])
    for (int k = tid; k < (TH + 7) * TW; k += 256) {
        int r = k / TW, c = k % TW;
        float m = A[r][c];
        #pragma unroll
        for (int d = 1; d < 8; ++d) m = fmaxf(m, A[r][c + d]);
        Bm[r][c] = m;
    }
    __syncthreads();

    // vertical + predicate
    for (int k = tid; k < TH * TW; k += 256) {
        int r = k / TW, c = k % TW;
        float v = A[r + 4][c + 4];
        if (v > MIN_INT) {
            float m = Bm[r][c];
            #pragma unroll
            for (int d = 1; d < 8; ++d) m = fmaxf(m, Bm[r + d][c]);
            if (m <= v) {                  // window max == v -> peak
                int p = (ty0 + r) * WV + (tx0 + c);
                uint64_t key = ((uint64_t)__float_as_uint(v) << 32)
                             | (uint64_t)(0xFFFFFFFFu - (uint32_t)p);
                int pos = atomicAdd(&lcnt, 1);        // LDS atomic only
                if (pos < LCAP) lkeys[pos] = key;     // overflow impossible here
            }
        }
    }
    __syncthreads();

    int take = lcnt < LCAP ? lcnt : LCAP;
    if (tid == 0) tcnt[b * GT + tile] = take;
    uint64_t* dst = cand + (size_t)(b * GT + tile) * LCAP;
    for (int k = tid; k < take; k += 256) dst[k] = lkeys[k];
}

// ---- kernel 2 (fused): per batch, top-50 selection + feature gather +
// 128x128 projection, all in one 512-thread block.
__global__ __launch_bounds__(512, 1)
void select_project_kernel(const uint64_t* __restrict__ cand,
                           const int* __restrict__ tcnt,
                           const float* __restrict__ vil,
                           const float* __restrict__ features,
                           const float* __restrict__ proj_w,
                           const float* __restrict__ proj_b,
                           float* __restrict__ out) {
    __shared__ uint64_t lists[NLISTS * LSTR];   // 36.9 KB
    __shared__ float g[NSTORM][NC];             // 25.6 KB
    __shared__ int offs[GT + 1];
    __shared__ int sel_idx_s[NSTORM];
    __shared__ int sel_valid_s[NSTORM];
    __shared__ uint64_t wred[8];
    __shared__ uint64_t bcast;

    int b = blockIdx.x;
    int tid = threadIdx.x;                 // 512
    const uint64_t* cb = cand + (size_t)b * GT * LCAP;

    if (tid < GT) offs[tid] = tcnt[b * GT + tid];
    __syncthreads();
    if (tid == 0) {
        int s = 0;
        for (int t = 0; t < GT; ++t) { int c = offs[t]; offs[t] = s; s += c; }
        offs[GT] = s;
    }
    __syncthreads();
    int n = offs[GT];
    int K = n < NSTORM ? n : NSTORM;

    if (n <= SELCAP) {
        // per-thread insertion sort of an 8-key chunk of the virtual
        // concatenation (binary search over tile offsets per element)
        int base = tid * LSTR, len = 0;
        for (int a = 0; a < SSZ; ++a) {
            int gi = tid * SSZ + a;
            uint64_t key = 0;
            if (gi < n) {
                int lo = 0, hi = GT;
                while (hi - lo > 1) { int mid = (lo + hi) >> 1;
                                      if (offs[mid] <= gi) lo = mid; else hi = mid; }
                key = cb[(size_t)lo * LCAP + (gi - offs[lo])];
            }
            int j = len - 1;
            while (j >= 0 && lists[base + j] < key) {
                lists[base + j + 1] = lists[base + j]; --j;
            }
            lists[base + j + 1] = key; ++len;
        }
        __syncthreads();
        // single-wave 512-way merge: lane owns 8 lists; keys unique, 0=sentinel
        if (tid < 64) {
            uint64_t v[8]; int h[8];
            #pragma unroll
            for (int i = 0; i < 8; ++i) { h[i] = 0; v[i] = lists[(tid * 8 + i) * LSTR]; }
            for (int t = 0; t < K; ++t) {
                uint64_t best = v[0];
                #pragma unroll
                for (int i = 1; i < 8; ++i) if (v[i] > best) best = v[i];
                #pragma unroll
                for (int off = 32; off > 0; off >>= 1) {
                    uint64_t o = __shfl_xor(best, off);
                    if (o > best) best = o;
                }
                #pragma unroll
                for (int i = 0; i < 8; ++i) {
                    if (v[i] == best) {
                        ++h[i];
                        v[i] = (h[i] < SSZ) ? lists[(tid * 8 + i) * LSTR + h[i]] : 0;
                    }
                }
                if (tid == 0) {
                    sel_idx_s[t] = (int)(~(uint32_t)(best & 0xFFFFFFFFu));
                    sel_valid_s[t] = 1;
                }
            }
        }
    } else {
        // dead safety path (n > 4096): iterative rescan of global lists
        uint64_t prev = ~0ull;
        for (int t = 0; t < K; ++t) {
            uint64_t best = 0;
            for (int gi = tid; gi < n; gi += 512) {
                int lo = 0, hi = GT;
                while (hi - lo > 1) { int mid = (lo + hi) >> 1;
                                      if (offs[mid] <= gi) lo = mid; else hi = mid; }
                uint64_t key = cb[(size_t)lo * LCAP + (gi - offs[lo])];
                if (key < prev && key > best) best = key;
            }
            #pragma unroll
            for (int off = 32; off > 0; off >>= 1) {
                uint64_t o = __shfl_xor(best, off);
                if (o > best) best = o;
            }
            if ((tid & 63) == 0) wred[tid >> 6] = best;
            __syncthreads();
            if (tid == 0) {
                uint64_t w = wred[0];
                #pragma unroll
                for (int i = 1; i < 8; ++i) if (wred[i] > w) w = wred[i];
                bcast = w;
                sel_idx_s[t] = (int)(~(uint32_t)(w & 0xFFFFFFFFu));
                sel_valid_s[t] = 1;
            }
            __syncthreads();
            prev = bcast;
        }
    }
    __syncthreads();

    // dead fallback: fewer than 50 peaks -> ascending non-peak indices,
    // zero peaks -> center (valid)
    if (tid == 0 && K < NSTORM) {
        const float* vb = vil + ((size_t)b * TFRAMES + (TFRAMES - 1)) * (HV * WV);
        int f = 0;
        for (int t = K; t < NSTORM; ++t) {
            while (f < HV * WV && is_peak(vb, f)) ++f;
            sel_idx_s[t] = f; sel_valid_s[t] = 0; ++f;
        }
        if (n == 0) { sel_idx_s[0] = (HV / 2) * WV + (WV / 2); sel_valid_s[0] = 1; }
    }
    __syncthreads();

    // gather: g[m][c] = features[b][c][yf][xf]  (scattered 4B loads)
    for (int q = tid; q < NSTORM * NC; q += 512) {
        int m = q >> 7, c = q & 127;
        int idx = sel_idx_s[m];
        int y = idx / WV, x = idx % WV;
        int yf = y >> 2; if (yf > HF - 1) yf = HF - 1;
        int xf = x >> 2; if (xf > WF - 1) xf = WF - 1;
        g[m][c] = features[((size_t)b * NC + c) * (HF * WF) + yf * WF + xf];
    }
    __syncthreads();

    // matvec: thread owns output dim d (w row in registers), loops storms
    int d = tid & 127, mg = tid >> 7;
    float4 wreg[32];
    const float4* w4 = (const float4*)(proj_w + (size_t)d * NC);
    #pragma unroll
    for (int q = 0; q < 32; ++q) wreg[q] = w4[q];
    float bias = proj_b[d];

    float* pos_out   = out + (size_t)NB * NSTORM * NC;
    float* valid_out = pos_out + (size_t)NB * NSTORM * 2;

    for (int m = mg; m < NSTORM; m += 4) {
        const float4* g4 = (const float4*)g[m];
        float acc = 0.f;
        #pragma unroll
        for (int q = 0; q < 32; ++q) {
            float4 gv = g4[q];
            acc += gv.x * wreg[q].x + gv.y * wreg[q].y
                 + gv.z * wreg[q].z + gv.w * wreg[q].w;
        }
        out[((size_t)b * NSTORM + m) * NC + d] =
            sel_valid_s[m] ? (acc + bias) : 0.f;
    }

    if (tid < NSTORM) {
        int idx = sel_idx_s[tid];
        int y = idx / WV, x = idx % WV;
        int yf = y >> 2; if (yf > HF - 1) yf = HF - 1;
        int xf = x >> 2; if (xf > WF - 1) xf = WF - 1;
        pos_out[(b * NSTORM + tid) * 2 + 0] = (float)yf;
        pos_out[(b * NSTORM + tid) * 2 + 1] = (float)xf;
        valid_out[b * NSTORM + tid] = sel_valid_s[tid] ? 1.f : 0.f;
    }
}

extern "C" void kernel_launch(void* const* d_in, const int* in_sizes, int n_in,
                              void* d_out, int out_size, void* d_ws, size_t ws_size,
                              hipStream_t stream) {
    const float* features = (const float*)d_in[0];
    const float* vil      = (const float*)d_in[1];
    const float* proj_w   = (const float*)d_in[2];
    const float* proj_b   = (const float*)d_in[3];
    float* out = (float*)d_out;

    uint8_t* ws = (uint8_t*)d_ws;
    int* tcnt      = (int*)ws;                        // 32*72 ints, all written
    uint64_t* cand = (uint64_t*)(ws + 16384);         // 32*72*256 u64 = 4.7 MB

    dim3 gA(GX, GY, NB);                   // 6 x 12 x 32
    peak_kernel<<<gA, 256, 0, stream>>>(vil, cand, tcnt);
    select_project_kernel<<<NB, 512, 0, stream>>>(cand, tcnt, vil, features,
                                                  proj_w, proj_b, out);
}